// Round 4
// baseline (349.860 us; speedup 1.0000x reference)
//
#include <hip/hip_runtime.h>

// ---------------------------------------------------------------------------
// DualGCN round 4: streaming register-resident-W MFMA GEMMs (no LDS, no
// barriers) + paired dispatches via blockIdx.y (independent branch a/b ops
// fused into single launches). bf16 slabs, fp32 accum everywhere.
// N=50000 (divisible by 16 -> 3125 full row-tiles), E=800000, H=128, OUT=64.
// Dispatches: rowptr_pair, convert_w, L0pair, Spair1, L1pair, Spair2, Lm, Lo.
// ---------------------------------------------------------------------------

typedef short short8 __attribute__((ext_vector_type(8)));
typedef float floatx4 __attribute__((ext_vector_type(4)));

__device__ inline unsigned short f2bf(float f) {
  unsigned u = __builtin_bit_cast(unsigned, f);
  u += 0x7fffu + ((u >> 16) & 1u);      // round-to-nearest-even
  return (unsigned short)(u >> 16);
}
__device__ inline unsigned pack2(float a, float b) {
  return (unsigned)f2bf(a) | ((unsigned)f2bf(b) << 16);
}
__device__ inline float bf_lo(unsigned w) {
  return __builtin_bit_cast(float, w << 16);
}
__device__ inline float bf_hi(unsigned w) {
  return __builtin_bit_cast(float, w & 0xffff0000u);
}

// ---------------------------------------------------------------------------
struct RpJob { const int* row; int* rowptr; };

// rowptr[i] = first edge index e with row[e] >= i  (row is sorted)
__global__ __launch_bounds__(256) void build_rowptr_pair_kernel(
    RpJob j0, RpJob j1, int E, int n)
{
  const RpJob J = blockIdx.y ? j1 : j0;
  int i = blockIdx.x * 256 + threadIdx.x;
  if (i > n) return;
  int lo = 0, hi = E;
  while (lo < hi) {
    int mid = (lo + hi) >> 1;
    if (J.row[mid] < i) lo = mid + 1; else hi = mid;
  }
  J.rowptr[i] = lo;
}

// all six weight matrices -> one concatenated bf16 buffer
// offsets: Wa0 0, Wa1 16384, Wb0 32768, Wb1 49152, Wm 65536, Wo 114688
__global__ __launch_bounds__(256) void convert_w_kernel(
    const float* __restrict__ Wa0, const float* __restrict__ Wa1,
    const float* __restrict__ Wb0, const float* __restrict__ Wb1,
    const float* __restrict__ Wm,  const float* __restrict__ Wo,
    unsigned short* __restrict__ out)
{
  int i = blockIdx.x * 256 + threadIdx.x;
  if (i >= 131072) return;
  float v;
  if      (i < 16384)  v = Wa0[i];
  else if (i < 32768)  v = Wa1[i - 16384];
  else if (i < 49152)  v = Wb0[i - 32768];
  else if (i < 65536)  v = Wb1[i - 49152];
  else if (i < 114688) v = Wm[i - 65536];
  else                 v = Wo[i - 114688];
  out[i] = f2bf(v);
}

// ---------------------------------------------------------------------------
struct SpmmJob {
  const int* rp; const int* col; const float* val;
  const unsigned short* X; unsigned short* Y;
};

// Y[r,:] = sum_e val[e] * X[col[e],:]  (bf16 in, fp32 accum, bf16 out)
// 16 lanes/row, lane owns 8 bf16 (16 B). Edge loop unrolled x8 -> 8
// independent 16 B gathers in flight per row-group. blockIdx.y selects job.
__global__ __launch_bounds__(256) void spmm_pair_kernel(
    SpmmJob j0, SpmmJob j1, int n)
{
  const SpmmJob J = blockIdx.y ? j1 : j0;
  const int g = blockIdx.x * 16 + (threadIdx.x >> 4);
  const int lane = threadIdx.x & 15;
  if (g >= n) return;
  const int e0 = J.rp[g], e1 = J.rp[g + 1];
  const size_t loff = (size_t)lane * 8;
  const unsigned short* __restrict__ X = J.X;

  float a0 = 0.f, a1 = 0.f, a2 = 0.f, a3 = 0.f;
  float a4 = 0.f, a5 = 0.f, a6 = 0.f, a7 = 0.f;

  auto accw = [&](float v, const uint4& w) {
    a0 = fmaf(v, bf_lo(w.x), a0); a1 = fmaf(v, bf_hi(w.x), a1);
    a2 = fmaf(v, bf_lo(w.y), a2); a3 = fmaf(v, bf_hi(w.y), a3);
    a4 = fmaf(v, bf_lo(w.z), a4); a5 = fmaf(v, bf_hi(w.z), a5);
    a6 = fmaf(v, bf_lo(w.w), a6); a7 = fmaf(v, bf_hi(w.w), a7);
  };
  auto acc1 = [&](int e) {
    uint4 w = *(const uint4*)(X + (size_t)J.col[e] * 128 + loff);
    accw(J.val[e], w);
  };

  int e = e0;
  int epro = (e0 + 7) & ~7;           // align to 8 for vector col/val loads
  if (epro > e1) epro = e1;
  for (; e < epro; ++e) acc1(e);
  for (; e + 8 <= e1; e += 8) {
    int4   ca = *(const int4*)(J.col + e);
    int4   cb = *(const int4*)(J.col + e + 4);
    float4 va = *(const float4*)(J.val + e);
    float4 vb = *(const float4*)(J.val + e + 4);
    uint4 w0 = *(const uint4*)(X + (size_t)ca.x * 128 + loff);
    uint4 w1 = *(const uint4*)(X + (size_t)ca.y * 128 + loff);
    uint4 w2 = *(const uint4*)(X + (size_t)ca.z * 128 + loff);
    uint4 w3 = *(const uint4*)(X + (size_t)ca.w * 128 + loff);
    uint4 w4 = *(const uint4*)(X + (size_t)cb.x * 128 + loff);
    uint4 w5 = *(const uint4*)(X + (size_t)cb.y * 128 + loff);
    uint4 w6 = *(const uint4*)(X + (size_t)cb.z * 128 + loff);
    uint4 w7 = *(const uint4*)(X + (size_t)cb.w * 128 + loff);
    accw(va.x, w0); accw(va.y, w1); accw(va.z, w2); accw(va.w, w3);
    accw(vb.x, w4); accw(vb.y, w5); accw(vb.z, w6); accw(vb.w, w7);
  }
  for (; e < e1; ++e) acc1(e);

  uint4 o;
  o.x = pack2(a0, a1); o.y = pack2(a2, a3);
  o.z = pack2(a4, a5); o.w = pack2(a6, a7);
  *(uint4*)(J.Y + (size_t)g * 128 + loff) = o;
}

// ---------------------------------------------------------------------------
struct LinJob {
  const void* X0; const void* X1; const void* X2;  // slabs (128 cols each)
  const unsigned short* W;   // [HOUT, K] bf16 row-major
  const float* b;            // [HOUT] fp32
  void* Y;                   // [n, HOUT] bf16 or fp32
};

// Streaming GEMM: Y = (relu?)(X @ W.T + b).
// Each wave: preload its W MFMA A-fragments into registers ONCE, then stream
// 16-row X tiles global->B-fragments->MFMA->store. No LDS, no barriers.
// blockIdx.y = job * NCB + col_block. Requires n % 16 == 0 (N=50000 ok).
// MFMA operand swap (a=W, b=X): lane (l15,quad) -> out row = tile*16+l15,
// out cols = cb*HB + j*16 + quad*4 + {0..3}.
template <int K, int HOUT, int HB, bool RELU, bool OUTBF, bool XFP32>
__global__ __launch_bounds__(256) void stream_linear_kernel(
    LinJob j0, LinJob j1, int tiles)
{
  constexpr int NCB = HOUT / HB;   // col-blocks per job
  constexpr int NT  = HB / 16;     // 16-col MFMA tiles per col-block
  constexpr int NK  = K / 32;      // 32-deep K steps

  const int yb = blockIdx.y;
  const LinJob J = (yb < NCB) ? j0 : j1;
  const int cb = (yb < NCB) ? yb : yb - NCB;

  const int lane = threadIdx.x & 63;
  const int wave = threadIdx.x >> 6;
  const int l15  = lane & 15;
  const int quad = lane >> 4;

  // W fragments: A[m=l15][k=quad*8+j], m = output col. Register-resident.
  short8 aW[NT][NK];
#pragma unroll
  for (int j = 0; j < NT; ++j)
#pragma unroll
    for (int kk = 0; kk < NK; ++kk)
      aW[j][kk] = *(const short8*)(
          J.W + (size_t)(cb * HB + j * 16 + l15) * K + kk * 32 + quad * 8);
  float4 bs[NT];
#pragma unroll
  for (int j = 0; j < NT; ++j)
    bs[j] = *(const float4*)(J.b + cb * HB + j * 16 + quad * 4);

  const int wgid  = blockIdx.x * 4 + wave;
  const int wstep = gridDim.x * 4;
  for (int t = wgid; t < tiles; t += wstep) {
    const int r = t * 16 + l15;
    short8 bX[NK];
    if (XFP32) {
      const float* Xr = (const float*)J.X0 + (size_t)r * 128;
#pragma unroll
      for (int kk = 0; kk < NK; ++kk) {
        float4 fa = *(const float4*)(Xr + kk * 32 + quad * 8);
        float4 fb = *(const float4*)(Xr + kk * 32 + quad * 8 + 4);
        uint4 u;
        u.x = pack2(fa.x, fa.y); u.y = pack2(fa.z, fa.w);
        u.z = pack2(fb.x, fb.y); u.w = pack2(fb.z, fb.w);
        bX[kk] = __builtin_bit_cast(short8, u);
      }
    } else {
#pragma unroll
      for (int kk = 0; kk < NK; ++kk) {
        const unsigned short* Xp = (const unsigned short*)(
            (kk < 4) ? J.X0 : (kk < 8) ? J.X1 : J.X2);
        bX[kk] = *(const short8*)(Xp + (size_t)r * 128 + (kk & 3) * 32 + quad * 8);
      }
    }
    floatx4 acc[NT];
#pragma unroll
    for (int j = 0; j < NT; ++j) acc[j] = (floatx4){0.f, 0.f, 0.f, 0.f};
#pragma unroll
    for (int kk = 0; kk < NK; ++kk)
#pragma unroll
      for (int j = 0; j < NT; ++j)
        acc[j] = __builtin_amdgcn_mfma_f32_16x16x32_bf16(
            aW[j][kk], bX[kk], acc[j], 0, 0, 0);
#pragma unroll
    for (int j = 0; j < NT; ++j) {
      float v0 = acc[j][0] + bs[j].x, v1 = acc[j][1] + bs[j].y;
      float v2 = acc[j][2] + bs[j].z, v3 = acc[j][3] + bs[j].w;
      if (RELU) {
        v0 = fmaxf(v0, 0.f); v1 = fmaxf(v1, 0.f);
        v2 = fmaxf(v2, 0.f); v3 = fmaxf(v3, 0.f);
      }
      const int c0 = cb * HB + j * 16 + quad * 4;
      if (OUTBF) {
        uint2 o; o.x = pack2(v0, v1); o.y = pack2(v2, v3);
        *(uint2*)((unsigned short*)J.Y + (size_t)r * HOUT + c0) = o;
      } else {
        float4 o; o.x = v0; o.y = v1; o.z = v2; o.w = v3;
        *(float4*)((float*)J.Y + (size_t)r * HOUT + c0) = o;
      }
    }
  }
}

// ---------------------------------------------------------------------------
extern "C" void kernel_launch(void* const* d_in, const int* in_sizes, int n_in,
                              void* d_out, int out_size, void* d_ws, size_t ws_size,
                              hipStream_t stream)
{
  const float* x     = (const float*)d_in[0];
  const int*   row_a = (const int*)d_in[1];
  const int*   col_a = (const int*)d_in[2];
  const float* val_a = (const float*)d_in[3];
  const int*   row_b = (const int*)d_in[4];
  const int*   col_b = (const int*)d_in[5];
  const float* val_b = (const float*)d_in[6];
  const float* Wa0 = (const float*)d_in[7];  const float* ba0 = (const float*)d_in[8];
  const float* Wa1 = (const float*)d_in[9];  const float* ba1 = (const float*)d_in[10];
  const float* Wb0 = (const float*)d_in[11]; const float* bb0 = (const float*)d_in[12];
  const float* Wb1 = (const float*)d_in[13]; const float* bb1 = (const float*)d_in[14];
  const float* Wm  = (const float*)d_in[15]; const float* bm  = (const float*)d_in[16];
  const float* Wo  = (const float*)d_in[17]; const float* bo  = (const float*)d_in[18];
  float* out = (float*)d_out;

  const int n = in_sizes[0] / 128;   // 50000
  const int E = in_sizes[1];         // 800000
  const int tiles = n / 16;          // 3125 (n % 16 == 0)

  char* ws = (char*)d_ws;
  size_t off = 0;
  auto alloc = [&](size_t bytes) {
    void* p = ws + off;
    off = (off + bytes + 255) & ~(size_t)255;
    return p;
  };
  int* rpa = (int*)alloc((size_t)(n + 1) * sizeof(int));
  int* rpb = (int*)alloc((size_t)(n + 1) * sizeof(int));
  unsigned short* Wcat = (unsigned short*)alloc(131072 * sizeof(unsigned short));
  const size_t slab = (size_t)n * 128 * sizeof(unsigned short);
  unsigned short* A  = (unsigned short*)alloc(slab);  // h / x_b
  unsigned short* B  = (unsigned short*)alloc(slab);  // Ba temp / g2
  unsigned short* C  = (unsigned short*)alloc(slab);  // g0
  unsigned short* D  = (unsigned short*)alloc(slab);  // g1
  unsigned short* Eo = (unsigned short*)alloc(slab);  // x_a
  unsigned short* F  = (unsigned short*)alloc(slab);  // Bb temp

  const unsigned short* Wa0b = Wcat;
  const unsigned short* Wa1b = Wcat + 16384;
  const unsigned short* Wb0b = Wcat + 32768;
  const unsigned short* Wb1b = Wcat + 49152;
  const unsigned short* Wmb  = Wcat + 65536;
  const unsigned short* Wob  = Wcat + 114688;

  dim3 blk(256);

  // rowptrs (paired)
  build_rowptr_pair_kernel<<<dim3((n + 1 + 255) / 256, 2), blk, 0, stream>>>(
      RpJob{row_a, rpa}, RpJob{row_b, rpb}, E, n);
  // weights -> bf16
  convert_w_kernel<<<dim3((131072 + 255) / 256), blk, 0, stream>>>(
      Wa0, Wa1, Wb0, Wb1, Wm, Wo, Wcat);

  // L0 pair: A = relu(x Wa0^T + ba0), C = relu(x Wb0^T + bb0)   [x fp32]
  stream_linear_kernel<128, 128, 64, true, true, true>
      <<<dim3(256, 4), blk, 0, stream>>>(
          LinJob{x, nullptr, nullptr, Wa0b, ba0, A},
          LinJob{x, nullptr, nullptr, Wb0b, bb0, C}, tiles);

  // S pair 1: B = spmm_a(A), F = spmm_b(C)
  spmm_pair_kernel<<<dim3((n + 15) / 16, 2), blk, 0, stream>>>(
      SpmmJob{rpa, col_a, val_a, A, B},
      SpmmJob{rpb, col_b, val_b, C, F}, n);

  // L1 pair: A = relu(B Wa1^T + ba1), D = relu(F Wb1^T + bb1)
  stream_linear_kernel<128, 128, 64, true, true, false>
      <<<dim3(256, 4), blk, 0, stream>>>(
          LinJob{B, nullptr, nullptr, Wa1b, ba1, A},
          LinJob{F, nullptr, nullptr, Wb1b, bb1, D}, tiles);

  // S pair 2: Eo = spmm_a(A) (x_a), B = spmm_b(D) (g2)
  spmm_pair_kernel<<<dim3((n + 15) / 16, 2), blk, 0, stream>>>(
      SpmmJob{rpa, col_a, val_a, A, Eo},
      SpmmJob{rpb, col_b, val_b, D, B}, n);

  // Lm: A = relu([C,D,B] Wm^T + bm)   (x_b)
  stream_linear_kernel<384, 128, 32, true, true, false>
      <<<dim3(256, 4), blk, 0, stream>>>(
          LinJob{C, D, B, Wmb, bm, A},
          LinJob{C, D, B, Wmb, bm, A}, tiles);

  // Lo: out = [Eo, A] Wo^T + bo   (fp32 out)
  stream_linear_kernel<256, 64, 64, false, false, false>
      <<<dim3(256, 1), blk, 0, stream>>>(
          LinJob{Eo, A, nullptr, Wob, bo, out},
          LinJob{Eo, A, nullptr, Wob, bo, out}, tiles);
}

// Round 6
// 332.052 us; speedup vs baseline: 1.0536x; 1.0536x over previous
//
#include <hip/hip_runtime.h>

// ---------------------------------------------------------------------------
// DualGCN round 6: LDS-tiled MFMA GEMMs (BM=64 row tiles, paired via
// blockIdx.y, fp32->bf16 conversion folded into L0 staging) + SpMM v3
// (pk_fma float2 accum, nontemporal col/val/Y via ext_vector_type,
// x8-unrolled gathers). bf16 slabs, fp32 accumulation everywhere.
// N=50000, E=800000, H=128, OUT=64.
// Dispatches: rowptr_pair, convert_w, L0pair, Spair1, L1pair, Spair2, Lm, Lo.
// ---------------------------------------------------------------------------

typedef short short8 __attribute__((ext_vector_type(8)));
typedef float floatx4 __attribute__((ext_vector_type(4)));
typedef float floatx2 __attribute__((ext_vector_type(2)));
typedef int   intx4   __attribute__((ext_vector_type(4)));
typedef float fltx4   __attribute__((ext_vector_type(4)));
typedef unsigned uintx4 __attribute__((ext_vector_type(4)));

__device__ inline unsigned short f2bf(float f) {
  unsigned u = __builtin_bit_cast(unsigned, f);
  u += 0x7fffu + ((u >> 16) & 1u);      // round-to-nearest-even
  return (unsigned short)(u >> 16);
}
__device__ inline unsigned pack2(float a, float b) {
  return (unsigned)f2bf(a) | ((unsigned)f2bf(b) << 16);
}
__device__ inline float bf_lo(unsigned w) {
  return __builtin_bit_cast(float, w << 16);
}
__device__ inline float bf_hi(unsigned w) {
  return __builtin_bit_cast(float, w & 0xffff0000u);
}

// ---------------------------------------------------------------------------
struct RpJob { const int* row; int* rowptr; };

__global__ __launch_bounds__(256) void build_rowptr_pair_kernel(
    RpJob j0, RpJob j1, int E, int n)
{
  const RpJob J = blockIdx.y ? j1 : j0;
  int i = blockIdx.x * 256 + threadIdx.x;
  if (i > n) return;
  int lo = 0, hi = E;
  while (lo < hi) {
    int mid = (lo + hi) >> 1;
    if (J.row[mid] < i) lo = mid + 1; else hi = mid;
  }
  J.rowptr[i] = lo;
}

// all six weight matrices -> one concatenated bf16 buffer
// offsets: Wa0 0, Wa1 16384, Wb0 32768, Wb1 49152, Wm 65536, Wo 114688
__global__ __launch_bounds__(256) void convert_w_kernel(
    const float* __restrict__ Wa0, const float* __restrict__ Wa1,
    const float* __restrict__ Wb0, const float* __restrict__ Wb1,
    const float* __restrict__ Wm,  const float* __restrict__ Wo,
    unsigned short* __restrict__ out)
{
  int i = blockIdx.x * 256 + threadIdx.x;
  if (i >= 131072) return;
  float v;
  if      (i < 16384)  v = Wa0[i];
  else if (i < 32768)  v = Wa1[i - 16384];
  else if (i < 49152)  v = Wb0[i - 32768];
  else if (i < 65536)  v = Wb1[i - 49152];
  else if (i < 114688) v = Wm[i - 65536];
  else                 v = Wo[i - 114688];
  out[i] = f2bf(v);
}

// ---------------------------------------------------------------------------
struct SpmmJob {
  const int* rp; const int* col; const float* val;
  const unsigned short* X; unsigned short* Y;
};

// Y[r,:] = sum_e val[e] * X[col[e],:]  (bf16 in, fp32 accum via v_pk_fma_f32,
// bf16 out). 16 lanes/row, lane owns 8 bf16 (16 B). Edge loop unrolled x8.
// col/val loaded nontemporal (streamed once); Y stored nontemporal -> keeps
// L2 capacity for the random X gathers.
__global__ __launch_bounds__(256) void spmm_pair_kernel(
    SpmmJob j0, SpmmJob j1, int n)
{
  const SpmmJob J = blockIdx.y ? j1 : j0;
  const int g = blockIdx.x * 16 + (threadIdx.x >> 4);
  const int lane = threadIdx.x & 15;
  if (g >= n) return;
  const int e0 = J.rp[g], e1 = J.rp[g + 1];
  const size_t loff = (size_t)lane * 8;
  const unsigned short* __restrict__ X = J.X;
  const int* __restrict__ colp = J.col;
  const float* __restrict__ valp = J.val;

  floatx2 ac0 = {0.f, 0.f}, ac1 = {0.f, 0.f};
  floatx2 ac2 = {0.f, 0.f}, ac3 = {0.f, 0.f};

  auto accw = [&](float v, const uintx4& w) {
    floatx2 vv = {v, v};
    floatx2 x0 = {bf_lo(w.x), bf_hi(w.x)};
    floatx2 x1 = {bf_lo(w.y), bf_hi(w.y)};
    floatx2 x2 = {bf_lo(w.z), bf_hi(w.z)};
    floatx2 x3 = {bf_lo(w.w), bf_hi(w.w)};
    ac0 = __builtin_elementwise_fma(vv, x0, ac0);
    ac1 = __builtin_elementwise_fma(vv, x1, ac1);
    ac2 = __builtin_elementwise_fma(vv, x2, ac2);
    ac3 = __builtin_elementwise_fma(vv, x3, ac3);
  };
  auto acc1 = [&](int e) {
    uintx4 w = *(const uintx4*)(X + (size_t)colp[e] * 128 + loff);
    accw(valp[e], w);
  };

  int e = e0;
  int epro = (e0 + 7) & ~7;           // align to 8 for vector col/val loads
  if (epro > e1) epro = e1;
  for (; e < epro; ++e) acc1(e);
  for (; e + 8 <= e1; e += 8) {
    intx4 ca = __builtin_nontemporal_load((const intx4*)(colp + e));
    intx4 cb = __builtin_nontemporal_load((const intx4*)(colp + e + 4));
    fltx4 va = __builtin_nontemporal_load((const fltx4*)(valp + e));
    fltx4 vb = __builtin_nontemporal_load((const fltx4*)(valp + e + 4));
    uintx4 w0 = *(const uintx4*)(X + (size_t)ca.x * 128 + loff);
    uintx4 w1 = *(const uintx4*)(X + (size_t)ca.y * 128 + loff);
    uintx4 w2 = *(const uintx4*)(X + (size_t)ca.z * 128 + loff);
    uintx4 w3 = *(const uintx4*)(X + (size_t)ca.w * 128 + loff);
    uintx4 w4 = *(const uintx4*)(X + (size_t)cb.x * 128 + loff);
    uintx4 w5 = *(const uintx4*)(X + (size_t)cb.y * 128 + loff);
    uintx4 w6 = *(const uintx4*)(X + (size_t)cb.z * 128 + loff);
    uintx4 w7 = *(const uintx4*)(X + (size_t)cb.w * 128 + loff);
    accw(va.x, w0); accw(va.y, w1); accw(va.z, w2); accw(va.w, w3);
    accw(vb.x, w4); accw(vb.y, w5); accw(vb.z, w6); accw(vb.w, w7);
  }
  for (; e < e1; ++e) acc1(e);

  uintx4 o;
  o.x = pack2(ac0[0], ac0[1]); o.y = pack2(ac1[0], ac1[1]);
  o.z = pack2(ac2[0], ac2[1]); o.w = pack2(ac3[0], ac3[1]);
  __builtin_nontemporal_store(o, (uintx4*)(J.Y + (size_t)g * 128 + loff));
}

// ---------------------------------------------------------------------------
struct LinJob {
  const void* X0; const void* X1; const void* X2;  // slabs (128 cols each)
  const unsigned short* W;   // [HOUT, K] bf16 row-major
  const float* b;            // [HOUT] fp32
  void* Y;                   // [n, HOUT] bf16 or fp32
};

// LDS-tiled MFMA GEMM: Y = (relu?)(X @ W.T + b).
// BM-row x HOUT-col block tile; K staged in 128-col chunks (slab-granular ->
// free concat). 4 waves in 2x2 (wm,wn); MFMA operand swap (a=W, b=X) so each
// lane's 4 acc regs are 4 consecutive output cols. XFP32: X0 is fp32,
// converted to bf16 during staging. blockIdx.y selects job.
template <int K, int HOUT, int BM, bool RELU, bool OUTBF, bool XFP32>
__global__ __launch_bounds__(256, 2) void mfma_linear_kernel(
    LinJob j0, LinJob j1, int n)
{
  constexpr int LDX = 136;        // padded LDS row stride (bf16 units)
  constexpr int NT = HOUT / 32;   // col tiles per wave
  constexpr int MT = BM / 32;     // row tiles per wave

  __shared__ unsigned short Xs[BM * LDX];
  __shared__ unsigned short Ws[HOUT * LDX];

  const LinJob J = blockIdx.y ? j1 : j0;
  const int tid  = threadIdx.x;
  const int lane = tid & 63;
  const int wave = tid >> 6;
  const int wm   = wave >> 1;
  const int wn   = wave & 1;
  const int l15  = lane & 15;
  const int quad = lane >> 4;
  const int row0 = blockIdx.x * BM;

  const int c8   = (tid & 15) * 8;  // 16 threads cover 128 cols (8 bf16 each)
  const int rloc = tid >> 4;        // 16 rows per staging pass

  floatx4 acc[MT][NT];
#pragma unroll
  for (int i = 0; i < MT; ++i)
#pragma unroll
    for (int j = 0; j < NT; ++j) acc[i][j] = (floatx4){0.f, 0.f, 0.f, 0.f};

  for (int kc = 0; kc < K; kc += 128) {
    // stage X tile: BM rows x 128 bf16
#pragma unroll
    for (int p = 0; p < BM / 16; ++p) {
      int r = p * 16 + rloc;
      int gr = row0 + r;
      uintx4 v = {0u, 0u, 0u, 0u};
      if (gr < n) {
        if (XFP32) {
          const float* Xr = (const float*)J.X0 + (size_t)gr * 128 + c8;
          fltx4 fa = *(const fltx4*)(Xr);
          fltx4 fb = *(const fltx4*)(Xr + 4);
          v.x = pack2(fa.x, fa.y); v.y = pack2(fa.z, fa.w);
          v.z = pack2(fb.x, fb.y); v.w = pack2(fb.z, fb.w);
        } else {
          const unsigned short* Xp = (const unsigned short*)(
              (kc == 0) ? J.X0 : (kc == 128) ? J.X1 : J.X2);
          v = *(const uintx4*)(Xp + (size_t)gr * 128 + c8);
        }
      }
      *(uintx4*)(Xs + r * LDX + c8) = v;
    }
    // stage W tile: HOUT rows x 128 bf16 (row stride K in global)
#pragma unroll
    for (int p = 0; p < HOUT / 16; ++p) {
      int r = p * 16 + rloc;
      uintx4 v = *(const uintx4*)(J.W + (size_t)r * K + kc + c8);
      *(uintx4*)(Ws + r * LDX + c8) = v;
    }
    __syncthreads();
#pragma unroll
    for (int k0 = 0; k0 < 128; k0 += 32) {
      const int ko = k0 + quad * 8;
      short8 aW[NT], bX[MT];
#pragma unroll
      for (int j = 0; j < NT; ++j)
        aW[j] = *(const short8*)(Ws + (wn * (16 * NT) + j * 16 + l15) * LDX + ko);
#pragma unroll
      for (int i = 0; i < MT; ++i)
        bX[i] = *(const short8*)(Xs + (wm * (16 * MT) + i * 16 + l15) * LDX + ko);
#pragma unroll
      for (int i = 0; i < MT; ++i)
#pragma unroll
        for (int j = 0; j < NT; ++j)
          acc[i][j] = __builtin_amdgcn_mfma_f32_16x16x32_bf16(
              aW[j], bX[i], acc[i][j], 0, 0, 0);
    }
    __syncthreads();
  }

#pragma unroll
  for (int i = 0; i < MT; ++i) {
    int r = row0 + wm * (16 * MT) + i * 16 + l15;
    if (r >= n) continue;
#pragma unroll
    for (int j = 0; j < NT; ++j) {
      int c0 = wn * (16 * NT) + j * 16 + quad * 4;
      fltx4 bb = *(const fltx4*)(J.b + c0);
      float v0 = acc[i][j][0] + bb.x;
      float v1 = acc[i][j][1] + bb.y;
      float v2 = acc[i][j][2] + bb.z;
      float v3 = acc[i][j][3] + bb.w;
      if (RELU) {
        v0 = fmaxf(v0, 0.f); v1 = fmaxf(v1, 0.f);
        v2 = fmaxf(v2, 0.f); v3 = fmaxf(v3, 0.f);
      }
      if (OUTBF) {
        uint2 o; o.x = pack2(v0, v1); o.y = pack2(v2, v3);
        *(uint2*)((unsigned short*)J.Y + (size_t)r * HOUT + c0) = o;
      } else {
        fltx4 o = {v0, v1, v2, v3};
        *(fltx4*)((float*)J.Y + (size_t)r * HOUT + c0) = o;
      }
    }
  }
}

// ---------------------------------------------------------------------------
extern "C" void kernel_launch(void* const* d_in, const int* in_sizes, int n_in,
                              void* d_out, int out_size, void* d_ws, size_t ws_size,
                              hipStream_t stream)
{
  const float* x     = (const float*)d_in[0];
  const int*   row_a = (const int*)d_in[1];
  const int*   col_a = (const int*)d_in[2];
  const float* val_a = (const float*)d_in[3];
  const int*   row_b = (const int*)d_in[4];
  const int*   col_b = (const int*)d_in[5];
  const float* val_b = (const float*)d_in[6];
  const float* Wa0 = (const float*)d_in[7];  const float* ba0 = (const float*)d_in[8];
  const float* Wa1 = (const float*)d_in[9];  const float* ba1 = (const float*)d_in[10];
  const float* Wb0 = (const float*)d_in[11]; const float* bb0 = (const float*)d_in[12];
  const float* Wb1 = (const float*)d_in[13]; const float* bb1 = (const float*)d_in[14];
  const float* Wm  = (const float*)d_in[15]; const float* bm  = (const float*)d_in[16];
  const float* Wo  = (const float*)d_in[17]; const float* bo  = (const float*)d_in[18];
  float* out = (float*)d_out;

  const int n = in_sizes[0] / 128;   // 50000
  const int E = in_sizes[1];         // 800000

  char* ws = (char*)d_ws;
  size_t off = 0;
  auto alloc = [&](size_t bytes) {
    void* p = ws + off;
    off = (off + bytes + 255) & ~(size_t)255;
    return p;
  };
  int* rpa = (int*)alloc((size_t)(n + 1) * sizeof(int));
  int* rpb = (int*)alloc((size_t)(n + 1) * sizeof(int));
  unsigned short* Wcat = (unsigned short*)alloc(131072 * sizeof(unsigned short));
  const size_t slab = (size_t)n * 128 * sizeof(unsigned short);
  unsigned short* A  = (unsigned short*)alloc(slab);  // h / x_b
  unsigned short* B  = (unsigned short*)alloc(slab);  // Ba temp / g2
  unsigned short* C  = (unsigned short*)alloc(slab);  // g0
  unsigned short* D  = (unsigned short*)alloc(slab);  // g1
  unsigned short* Eo = (unsigned short*)alloc(slab);  // x_a
  unsigned short* F  = (unsigned short*)alloc(slab);  // Bb temp

  const unsigned short* Wa0b = Wcat;
  const unsigned short* Wa1b = Wcat + 16384;
  const unsigned short* Wb0b = Wcat + 32768;
  const unsigned short* Wb1b = Wcat + 49152;
  const unsigned short* Wmb  = Wcat + 65536;
  const unsigned short* Wob  = Wcat + 114688;

  dim3 blk(256);
  const int nb64 = (n + 63) / 64;    // 782

  // rowptrs (paired) + weights
  build_rowptr_pair_kernel<<<dim3((n + 1 + 255) / 256, 2), blk, 0, stream>>>(
      RpJob{row_a, rpa}, RpJob{row_b, rpb}, E, n);
  convert_w_kernel<<<dim3((131072 + 255) / 256), blk, 0, stream>>>(
      Wa0, Wa1, Wb0, Wb1, Wm, Wo, Wcat);

  // L0 pair: A = relu(x Wa0^T + ba0), C = relu(x Wb0^T + bb0)   [x fp32]
  mfma_linear_kernel<128, 128, 64, true, true, true>
      <<<dim3(nb64, 2), blk, 0, stream>>>(
          LinJob{x, nullptr, nullptr, Wa0b, ba0, A},
          LinJob{x, nullptr, nullptr, Wb0b, bb0, C}, n);

  // S pair 1: B = spmm_a(A), F = spmm_b(C)
  spmm_pair_kernel<<<dim3((n + 15) / 16, 2), blk, 0, stream>>>(
      SpmmJob{rpa, col_a, val_a, A, B},
      SpmmJob{rpb, col_b, val_b, C, F}, n);

  // L1 pair: A = relu(B Wa1^T + ba1), D = relu(F Wb1^T + bb1)
  mfma_linear_kernel<128, 128, 64, true, true, false>
      <<<dim3(nb64, 2), blk, 0, stream>>>(
          LinJob{B, nullptr, nullptr, Wa1b, ba1, A},
          LinJob{F, nullptr, nullptr, Wb1b, bb1, D}, n);

  // S pair 2: Eo = spmm_a(A) (x_a), B = spmm_b(D) (g2)
  spmm_pair_kernel<<<dim3((n + 15) / 16, 2), blk, 0, stream>>>(
      SpmmJob{rpa, col_a, val_a, A, Eo},
      SpmmJob{rpb, col_b, val_b, D, B}, n);

  // Lm: A = relu([C,D,B] Wm^T + bm)   (x_b)
  mfma_linear_kernel<384, 128, 64, true, true, false>
      <<<dim3(nb64, 1), blk, 0, stream>>>(
          LinJob{C, D, B, Wmb, bm, A},
          LinJob{C, D, B, Wmb, bm, A}, n);

  // Lo: out = [Eo, A] Wo^T + bo   (fp32 out)
  mfma_linear_kernel<256, 64, 64, false, false, false>
      <<<dim3(nb64, 1), blk, 0, stream>>>(
          LinJob{Eo, A, nullptr, Wob, bo, out},
          LinJob{Eo, A, nullptr, Wob, bo, out}, n);
}